// Round 11
// baseline (313.442 us; speedup 1.0000x reference)
//
#include <hip/hip_runtime.h>
#include <cstdint>

#define NN 16000
#define KK 16
#define FIN 32
#define HH 64
#define NE (NN*KK)
#define GG 64
#define NCELL (GG*GG)
#define NBLK 250            // mega-kernel grid: 250 blocks <= 256 CUs -> co-resident

// ---------------------------------------------------------------- grid barrier (device-scope)
__device__ __forceinline__ void grid_barrier(unsigned* ctr, unsigned target) {
  __syncthreads();
  if (threadIdx.x == 0) {
    __threadfence();                               // release all prior writes
    __hip_atomic_fetch_add(ctr, 1u, __ATOMIC_ACQ_REL, __HIP_MEMORY_SCOPE_AGENT);
    unsigned spins = 0;
    while (__hip_atomic_load(ctr, __ATOMIC_ACQUIRE, __HIP_MEMORY_SCOPE_AGENT) < target) {
      __builtin_amdgcn_s_sleep(8);
      if (++spins > 200000000u) break;             // fail loud, never hang
    }
    __threadfence();                               // acquire: see others' writes
  }
  __syncthreads();
}

// ---------------------------------------------------------------- dispatch 1: binsort (block 0) + gemm1 (blocks 1..250)
// binsort: pack[i]=(x,y,sq,idxbits), sq = round(x^2)+round(y^2) UNFUSED (np c*c+sum);
// LDS histogram -> wave-shuffle scan -> LDS-cursor scatter. Within-cell order is
// arbitrary but all downstream outputs are order-invariant (unique keys, per-node math).
__global__ __launch_bounds__(1024) void binsort_gemm1_kernel(const float* __restrict__ c,
                                                             const float* __restrict__ x,
                                                             const float* __restrict__ w1,
                                                             float4* __restrict__ pack,
                                                             unsigned* __restrict__ cellid,
                                                             unsigned* __restrict__ cstart,
                                                             float4* __restrict__ sorted,
                                                             int* __restrict__ sid,
                                                             float* __restrict__ xw1,
                                                             unsigned* __restrict__ gmm,
                                                             unsigned* __restrict__ bctr) {
#pragma clang fp contract(off)
  const int tid = threadIdx.x;
  if (blockIdx.x > 0) {
    // ---------------- gemm1: xw1 = x @ W1 (KIN=32), 4 features/thread — R10 verbatim math
    int gid = (int)(blockIdx.x - 1) * 1024 + tid;   // 0..255999
    int i = gid >> 4, fq = gid & 15;
    const float4* ar = (const float4*)(x + i * FIN);
    float4 A[FIN/4];
#pragma unroll
    for (int qq = 0; qq < FIN/4; ++qq) A[qq] = ar[qq];
    float4 acc = make_float4(0.f, 0.f, 0.f, 0.f);
#pragma unroll
    for (int k = 0; k < FIN; ++k) {
      float av = ((const float*)A)[k];
      float4 wv4 = *(const float4*)(w1 + k*HH + 4*fq);
      acc.x = fmaf(av, wv4.x, acc.x);
      acc.y = fmaf(av, wv4.y, acc.y);
      acc.z = fmaf(av, wv4.z, acc.z);
      acc.w = fmaf(av, wv4.w, acc.w);
    }
    *(float4*)(xw1 + i*HH + 4*fq) = acc;
    return;
  }
  // ---------------- binsort (single block, 1024 threads)
  __shared__ unsigned hist[NCELL];                  // 16 KB
  __shared__ unsigned wsum[16];
  const int lane = tid & 63, wv = tid >> 6;
  if (tid == 0) { gmm[0] = 0x7F800000u; gmm[1] = 0u; *bctr = 0u; }
  for (int j = tid; j < NCELL; j += 1024) hist[j] = 0u;
  __syncthreads();
  for (int i = tid; i < NN; i += 1024) {
    float xv = c[2*i], yv = c[2*i+1];
    float xx = xv * xv;                             // round(x^2) (no fma: contract off)
    float yy = yv * yv;                             // round(y^2)
    float sq = xx + yy;                             // round(xx+yy)
    pack[i] = make_float4(xv, yv, sq, __uint_as_float((unsigned)i));
    int cx = (int)(xv * GG); cx = cx > GG-1 ? GG-1 : (cx < 0 ? 0 : cx);
    int cy = (int)(yv * GG); cy = cy > GG-1 ? GG-1 : (cy < 0 ? 0 : cy);
    unsigned cell = (unsigned)(cy * GG + cx);
    cellid[i] = cell;
    atomicAdd(&hist[cell], 1u);
  }
  __syncthreads();
  // scan: 4 cells/thread, wave-shuffle inclusive scan + wave-total scan
  unsigned h0 = hist[tid*4+0], h1 = hist[tid*4+1], h2 = hist[tid*4+2], h3 = hist[tid*4+3];
  unsigned s = h0 + h1 + h2 + h3;
  unsigned v = s;
#pragma unroll
  for (int off = 1; off < 64; off <<= 1) {
    unsigned u = __shfl_up(v, off, 64);
    if (lane >= off) v += u;
  }
  if (lane == 63) wsum[wv] = v;
  __syncthreads();
  if (wv == 0) {
    unsigned t = (lane < 16) ? wsum[lane] : 0u;
    unsigned vv = t;
#pragma unroll
    for (int off = 1; off < 16; off <<= 1) {
      unsigned u = __shfl_up(vv, off, 64);
      if (lane >= off) vv += u;
    }
    if (lane < 16) wsum[lane] = vv - t;             // exclusive
  }
  __syncthreads();
  unsigned b = wsum[wv] + v - s;                    // exclusive prefix of first owned cell
  unsigned cur0 = b;             cstart[tid*4+0] = b; b += h0;
  unsigned cur1 = b;             cstart[tid*4+1] = b; b += h1;
  unsigned cur2 = b;             cstart[tid*4+2] = b; b += h2;
  unsigned cur3 = b;             cstart[tid*4+3] = b; b += h3;
  hist[tid*4+0] = cur0; hist[tid*4+1] = cur1; hist[tid*4+2] = cur2; hist[tid*4+3] = cur3;
  if (tid == 1023) cstart[NCELL] = b;               // == NN
  __syncthreads();
  // scatter via LDS cursors
  for (int i = tid; i < NN; i += 1024) {
    unsigned p = atomicAdd(&hist[cellid[i]], 1u);
    sorted[p] = pack[i];
    sid[p] = i;
  }
}

// ---------------------------------------------------------------- dispatch 2: mega kernel
// Phase A: knn (4 lanes/node, pipelined, count-stop) + edge epilogue  [R10 verbatim]
// Phase B: ewdeg.  Phase C: agg1+relu+gemm2.  Phase D: agg2+relu+fc.
// Grid barriers between phases (all 250 blocks co-resident).
__global__ __launch_bounds__(256) void mega_kernel(const float4* __restrict__ sorted,
                                                   const unsigned* __restrict__ cstart,
                                                   const float* __restrict__ c,
                                                   int* __restrict__ nbr,
                                                   float* __restrict__ ew,     // d then ew in-place
                                                   unsigned* __restrict__ gmm,
                                                   float* __restrict__ dis,
                                                   const int* __restrict__ sid,
                                                   const float* __restrict__ xw1,
                                                   const float* __restrict__ b1,
                                                   const float* __restrict__ w2,
                                                   float* __restrict__ xw2,
                                                   const float* __restrict__ b2,
                                                   const float* __restrict__ wfc,
                                                   const float* __restrict__ bfc,
                                                   float* __restrict__ out,
                                                   unsigned* __restrict__ bctr) {
#pragma clang fp contract(off)
  const int tid = threadIdx.x;
  const int lane = tid & 63;
  const int wv = tid >> 6;

  // ================= Phase A: knn + edge =================
  {
    const int g = blockIdx.x * 256 + tid;
    const int t = g >> 2;                            // sorted node index (0..15999)
    const int q = g & 3;                             // quad lane
    const float4 me = sorted[t];
    const int myid = (int)__float_as_uint(me.w);
    const float h = 1.0f / GG;                       // exact 2^-6
    int cx = (int)(me.x * GG); cx = cx > GG-1 ? GG-1 : (cx < 0 ? 0 : cx);
    int cy = (int)(me.y * GG); cy = cy > GG-1 ? GG-1 : (cy < 0 ? 0 : cy);

    unsigned long long kd[KK];
#pragma unroll
    for (int m = 0; m < KK; ++m) kd[m] = ~0ull;

    auto process = [&](float4 cand) {
      int j = (int)__float_as_uint(cand.w);
      float xprod = me.x * cand.x;                       // round(x_i*x_j)
      float dot   = __builtin_fmaf(me.y, cand.y, xprod); // BLAS K=2 fma
      float S     = me.z + cand.z;                       // round(sq_i+sq_j)
      float twod  = dot + dot;                           // exact *2
      float d2    = S - twod;                            // one rounding
      unsigned ub = __float_as_uint(d2);
      ub = (ub & 0x80000000u) ? ~ub : (ub | 0x80000000u);
      unsigned long long key = ((unsigned long long)ub << 32) | (unsigned)j;
      if (j != myid && key < kd[KK-1]) {
        unsigned long long ck = key;
#pragma unroll
        for (int m = 0; m < KK; ++m) {
          bool sw = ck < kd[m];
          unsigned long long lo = sw ? ck : kd[m];
          unsigned long long hi = sw ? kd[m] : ck;
          kd[m] = lo; ck = hi;
        }
      }
    };
    auto scanSpan = [&](unsigned p0, unsigned p1) {   // software-pipelined
      unsigned pp = p0 + (unsigned)q;
      if (pp >= p1) return;
      float4 cur = sorted[pp];
      unsigned pn = pp + 4;
      while (pn < p1) {
        float4 nxt = sorted[pn];
        process(cur);
        cur = nxt;
        pn += 4;
      }
      process(cur);
    };
    auto scanRow = [&](int y, int x0, int x1) {
      unsigned p0 = cstart[y*GG + x0];
      unsigned p1 = cstart[y*GG + x1 + 1];
      scanSpan(p0, p1);
    };

    int lxa = cx-2 < 0 ? 0 : cx-2;
    int lxb = cx+2 > GG-1 ? GG-1 : cx+2;
    int lya = cy-2 < 0 ? 0 : cy-2;
    int lyb = cy+2 > GG-1 ? GG-1 : cy+2;
    {
      unsigned rb0[5], rb1[5];
      int nr = lyb - lya + 1;
#pragma unroll
      for (int k = 0; k < 5; ++k) {
        int y = lya + k;
        if (k < nr) {
          rb0[k] = cstart[y*GG + lxa];
          rb1[k] = cstart[y*GG + lxb + 1];
        }
      }
#pragma unroll
      for (int k = 0; k < 5; ++k)
        if (k < nr) scanSpan(rb0[k], rb1[k]);
    }

    int R = 2;
    while (true) {
      bool whole = (lxa <= 0) && (lxb >= GG-1) && (lya <= 0) && (lyb >= GG-1);
      bool done = whole;
      if (!done) {
        float edge = 1e30f;
        if (lxa > 0)    edge = fminf(edge, me.x - (float)lxa * h);
        if (lxb < GG-1) edge = fminf(edge, (float)(lxb+1) * h - me.x);
        if (lya > 0)    edge = fminf(edge, me.y - (float)lya * h);
        if (lyb < GG-1) edge = fminf(edge, (float)(lyb+1) * h - me.y);
        float lim = edge * edge - 1e-5f;             // margin >> Gram noise (~1e-6)
        if (lim > 0.0f) {
          unsigned lb = __float_as_uint(lim) | 0x80000000u;
          int cle = 0;
#pragma unroll
          for (int m = 0; m < KK; ++m) cle += ((unsigned)(kd[m] >> 32) <= lb) ? 1 : 0;
          cle += __shfl_xor(cle, 1, 64);
          cle += __shfl_xor(cle, 2, 64);
          done = cle >= KK;
        }
      }
      if (done) break;
      ++R;
      int nxa = cx-R < 0 ? 0 : cx-R;
      int nxb = cx+R > GG-1 ? GG-1 : cx+R;
      int nya = cy-R < 0 ? 0 : cy-R;
      int nyb = cy+R > GG-1 ? GG-1 : cy+R;
      if (nya < lya) scanRow(nya, nxa, nxb);
      if (nyb > lyb) scanRow(nyb, nxa, nxb);
      if (nxa < lxa) for (int y = lya; y <= lyb; ++y) scanRow(y, nxa, nxa);
      if (nxb > lxb) for (int y = lya; y <= lyb; ++y) scanRow(y, nxb, nxb);
      lxa = nxa; lxb = nxb; lya = nya; lyb = nyb;
    }

    unsigned res[4];
    for (int r = 0; r < KK; ++r) {
      unsigned long long md = kd[0];
      unsigned long long m1 = __shfl_xor(md, 1, 64); md = m1 < md ? m1 : md;
      unsigned long long m2 = __shfl_xor(md, 2, 64); md = m2 < md ? m2 : md;
      if (kd[0] == md) {
#pragma unroll
        for (int m = 0; m < KK-1; ++m) kd[m] = kd[m+1];
        kd[KK-1] = ~0ull;
      }
      if ((r >> 2) == q) res[r & 3] = (unsigned)(md & 0xFFFFFFFFull);
    }

    int4 w4; w4.x = (int)res[0]; w4.y = (int)res[1]; w4.z = (int)res[2]; w4.w = (int)res[3];
    *(int4*)(nbr + myid*KK + 4*q) = w4;
    unsigned bmin = 0xFFFFFFFFu, bmax = 0u;
#pragma unroll
    for (int e = 0; e < 4; ++e) {
      int j = (int)res[e];
      float dx = me.x - c[2*j];
      float dy = me.y - c[2*j+1];
      float xx = dx * dx;
      float yy = dy * dy;
      float d  = __builtin_sqrtf(xx + yy);
      ew[myid*KK + 4*q + e] = d;                     // d now, ew after phase B
      unsigned bb = __float_as_uint(d);
      bmin = bmin < bb ? bmin : bb;
      bmax = bmax > bb ? bmax : bb;
    }
#pragma unroll
    for (int off = 32; off > 0; off >>= 1) {
      unsigned ob = __shfl_xor(bmin, off, 64);
      bmin = bmin < ob ? bmin : ob;
      unsigned oB = __shfl_xor(bmax, off, 64);
      bmax = bmax > oB ? bmax : oB;
    }
    if (lane == 0) {
      atomicMin(&gmm[0], bmin);
      atomicMax(&gmm[1], bmax);
    }
  }

  grid_barrier(bctr, NBLK);

  // ================= Phase B: ew + deg + dis =================
  if (tid < 64) {
    int i = blockIdx.x * 64 + tid;                   // 250*64 == NN exactly
    float mx  = __uint_as_float(gmm[1]);
    float rng = mx - __uint_as_float(gmm[0]);
    float deg = 0.0f;                                // edges first, self-loop last
    float4* dp = (float4*)(ew + i*KK);
#pragma unroll
    for (int qq = 0; qq < 4; ++qq) {
      float4 v4 = dp[qq];
      float e0 = (mx - v4.x) / rng;
      float e1 = (mx - v4.y) / rng;
      float e2 = (mx - v4.z) / rng;
      float e3 = (mx - v4.w) / rng;
      deg = deg + e0; deg = deg + e1;
      deg = deg + e2; deg = deg + e3;
      dp[qq] = make_float4(e0, e1, e2, e3);
    }
    deg = deg + 1.0f;                                // self-loop weight 1, added last
    dis[i] = 1.0f / __builtin_sqrtf(deg);            // deg >= 1
  }

  grid_barrier(bctr, 2*NBLK);

  // ================= Phase C: agg1 + relu + gemm2 =================
  for (int it = 0; it < 16; ++it) {
    int i = sid[blockIdx.x*64 + it*4 + wv];
    float di = dis[i];
    float acc = 0.0f;
#pragma unroll 4
    for (int k = 0; k < KK; ++k) {
      int s = nbr[i*KK + k];
      float coef = (dis[s] * ew[i*KK + k]) * di;     // (dis[s]*w)*dis[t]
      acc = fmaf(coef, xw1[s*HH + lane], acc);
    }
    acc = fmaf(di * di, xw1[i*HH + lane], acc);      // self loop last
    float hv = fmaxf(acc + b1[lane], 0.0f);          // h1[i][lane]
    float acc2 = 0.0f;
#pragma unroll 16
    for (int k = 0; k < HH; ++k) {
      float hk = __shfl(hv, k, 64);
      acc2 = fmaf(hk, w2[k*HH + lane], acc2);
    }
    xw2[i*HH + lane] = acc2;
  }

  grid_barrier(bctr, 3*NBLK);

  // ================= Phase D: agg2 + relu + fc =================
  for (int it = 0; it < 16; ++it) {
    int i = sid[blockIdx.x*64 + it*4 + wv];
    float di = dis[i];
    float acc = 0.0f;
#pragma unroll 4
    for (int k = 0; k < KK; ++k) {
      int s = nbr[i*KK + k];
      float coef = (dis[s] * ew[i*KK + k]) * di;
      acc = fmaf(coef, xw2[s*HH + lane], acc);
    }
    acc = fmaf(di * di, xw2[i*HH + lane], acc);
    float v = fmaxf(acc + b2[lane], 0.0f);           // h2 feature
    float p = v * wfc[lane];                         // h2 @ Wfc (F_OUT = 1)
#pragma unroll
    for (int off = 32; off > 0; off >>= 1) p = p + __shfl_xor(p, off, 64);
    if (lane == 0) out[i] = p + bfc[0];
  }
}

// ---------------------------------------------------------------- launch
extern "C" void kernel_launch(void* const* d_in, const int* in_sizes, int n_in,
                              void* d_out, int out_size, void* d_ws, size_t ws_size,
                              hipStream_t stream) {
  (void)in_sizes; (void)n_in; (void)out_size; (void)ws_size;
  const float* x   = (const float*)d_in[0];
  const float* c   = (const float*)d_in[1];
  const float* W1  = (const float*)d_in[2];
  const float* b1  = (const float*)d_in[3];
  const float* W2  = (const float*)d_in[4];
  const float* b2  = (const float*)d_in[5];
  const float* Wfc = (const float*)d_in[6];
  const float* bfc = (const float*)d_in[7];
  float* out = (float*)d_out;

  char* ws = (char*)d_ws;
  size_t off = 0;
  auto alloc = [&](size_t bytes) -> void* {
    void* p = ws + off;
    off += (bytes + 255) & ~size_t(255);
    return p;
  };
  float4*   pack   = (float4*)  alloc(NN * sizeof(float4));       // 256 KB
  float4*   sorted = (float4*)  alloc(NN * sizeof(float4));       // 256 KB
  unsigned* cstart = (unsigned*)alloc((NCELL+1) * sizeof(unsigned));
  unsigned* cellid = (unsigned*)alloc(NN * sizeof(unsigned));     // 64 KB
  int*      sid    = (int*)     alloc(NN * sizeof(int));          // 64 KB
  int*      nbr    = (int*)     alloc(NE * sizeof(int));          // 1 MB
  float*    ew     = (float*)   alloc(NE * sizeof(float));        // 1 MB (d then ew in-place)
  float*    dis    = (float*)   alloc(NN * sizeof(float));        // 64 KB
  unsigned* gmm    = (unsigned*)alloc(2 * sizeof(unsigned));
  unsigned* bctr   = (unsigned*)alloc(sizeof(unsigned));
  float*    xw1    = (float*)   alloc(NN * HH * sizeof(float));   // 4 MB
  float*    xw2    = (float*)   alloc(NN * HH * sizeof(float));   // 4 MB

  binsort_gemm1_kernel<<<251, 1024, 0, stream>>>(c, x, W1, pack, cellid, cstart,
                                                 sorted, sid, xw1, gmm, bctr);
  mega_kernel<<<NBLK, 256, 0, stream>>>(sorted, cstart, c, nbr, ew, gmm, dis, sid,
                                        xw1, b1, W2, xw2, b2, Wfc, bfc, out, bctr);
}

// Round 12
// 259.590 us; speedup vs baseline: 1.2075x; 1.2075x over previous
//
#include <hip/hip_runtime.h>
#include <cstdint>

#define NN 16000
#define KK 16
#define FIN 32
#define HH 64
#define NE (NN*KK)
#define GG 64
#define NCELL (GG*GG)
#define NBLK 250            // knn/ewdeg grid: 250 blocks <= 256 CUs -> co-resident

// ---------------------------------------------------------------- grid barrier (device-scope)
__device__ __forceinline__ void grid_barrier(unsigned* ctr, unsigned target) {
  __syncthreads();
  if (threadIdx.x == 0) {
    __threadfence();                               // release all prior writes
    __hip_atomic_fetch_add(ctr, 1u, __ATOMIC_ACQ_REL, __HIP_MEMORY_SCOPE_AGENT);
    unsigned spins = 0;
    while (__hip_atomic_load(ctr, __ATOMIC_ACQUIRE, __HIP_MEMORY_SCOPE_AGENT) < target) {
      __builtin_amdgcn_s_sleep(8);
      if (++spins > 200000000u) break;             // fail loud, never hang
    }
    __threadfence();                               // acquire: see others' writes
  }
  __syncthreads();
}

// ---------------------------------------------------------------- dispatch 1: binsort (block 0) + gemm1 (blocks 1..250)
// binsort: pack[i]=(x,y,sq,idxbits), sq = round(x^2)+round(y^2) UNFUSED (np c*c+sum);
// LDS histogram -> wave-shuffle scan -> LDS-cursor scatter. Within-cell order is
// arbitrary but all downstream outputs are order-invariant (unique keys, per-node math).
__global__ __launch_bounds__(1024) void binsort_gemm1_kernel(const float* __restrict__ c,
                                                             const float* __restrict__ x,
                                                             const float* __restrict__ w1,
                                                             float4* __restrict__ pack,
                                                             unsigned* __restrict__ cellid,
                                                             unsigned* __restrict__ cstart,
                                                             float4* __restrict__ sorted,
                                                             int* __restrict__ sid,
                                                             float* __restrict__ xw1,
                                                             unsigned* __restrict__ gmm,
                                                             unsigned* __restrict__ bctr) {
#pragma clang fp contract(off)
  const int tid = threadIdx.x;
  if (blockIdx.x > 0) {
    // ---------------- gemm1: xw1 = x @ W1 (KIN=32), 4 features/thread
    int gid = (int)(blockIdx.x - 1) * 1024 + tid;   // 0..255999
    int i = gid >> 4, fq = gid & 15;
    const float4* ar = (const float4*)(x + i * FIN);
    float4 A[FIN/4];
#pragma unroll
    for (int qq = 0; qq < FIN/4; ++qq) A[qq] = ar[qq];
    float4 acc = make_float4(0.f, 0.f, 0.f, 0.f);
#pragma unroll
    for (int k = 0; k < FIN; ++k) {
      float av = ((const float*)A)[k];
      float4 wv4 = *(const float4*)(w1 + k*HH + 4*fq);
      acc.x = fmaf(av, wv4.x, acc.x);
      acc.y = fmaf(av, wv4.y, acc.y);
      acc.z = fmaf(av, wv4.z, acc.z);
      acc.w = fmaf(av, wv4.w, acc.w);
    }
    *(float4*)(xw1 + i*HH + 4*fq) = acc;
    return;
  }
  // ---------------- binsort (single block, 1024 threads)
  __shared__ unsigned hist[NCELL];                  // 16 KB
  __shared__ unsigned wsum[16];
  const int lane = tid & 63, wv = tid >> 6;
  if (tid == 0) { gmm[0] = 0x7F800000u; gmm[1] = 0u; *bctr = 0u; }
  for (int j = tid; j < NCELL; j += 1024) hist[j] = 0u;
  __syncthreads();
  for (int i = tid; i < NN; i += 1024) {
    float xv = c[2*i], yv = c[2*i+1];
    float xx = xv * xv;                             // round(x^2) (no fma: contract off)
    float yy = yv * yv;                             // round(y^2)
    float sq = xx + yy;                             // round(xx+yy)
    pack[i] = make_float4(xv, yv, sq, __uint_as_float((unsigned)i));
    int cx = (int)(xv * GG); cx = cx > GG-1 ? GG-1 : (cx < 0 ? 0 : cx);
    int cy = (int)(yv * GG); cy = cy > GG-1 ? GG-1 : (cy < 0 ? 0 : cy);
    unsigned cell = (unsigned)(cy * GG + cx);
    cellid[i] = cell;
    atomicAdd(&hist[cell], 1u);
  }
  __syncthreads();
  unsigned h0 = hist[tid*4+0], h1 = hist[tid*4+1], h2 = hist[tid*4+2], h3 = hist[tid*4+3];
  unsigned s = h0 + h1 + h2 + h3;
  unsigned v = s;
#pragma unroll
  for (int off = 1; off < 64; off <<= 1) {
    unsigned u = __shfl_up(v, off, 64);
    if (lane >= off) v += u;
  }
  if (lane == 63) wsum[wv] = v;
  __syncthreads();
  if (wv == 0) {
    unsigned t = (lane < 16) ? wsum[lane] : 0u;
    unsigned vv = t;
#pragma unroll
    for (int off = 1; off < 16; off <<= 1) {
      unsigned u = __shfl_up(vv, off, 64);
      if (lane >= off) vv += u;
    }
    if (lane < 16) wsum[lane] = vv - t;             // exclusive
  }
  __syncthreads();
  unsigned b = wsum[wv] + v - s;
  unsigned cur0 = b;             cstart[tid*4+0] = b; b += h0;
  unsigned cur1 = b;             cstart[tid*4+1] = b; b += h1;
  unsigned cur2 = b;             cstart[tid*4+2] = b; b += h2;
  unsigned cur3 = b;             cstart[tid*4+3] = b; b += h3;
  hist[tid*4+0] = cur0; hist[tid*4+1] = cur1; hist[tid*4+2] = cur2; hist[tid*4+3] = cur3;
  if (tid == 1023) cstart[NCELL] = b;               // == NN
  __syncthreads();
  for (int i = tid; i < NN; i += 1024) {
    unsigned p = atomicAdd(&hist[cellid[i]], 1u);
    sorted[p] = pack[i];
    sid[p] = i;
  }
}

// ---------------------------------------------------------------- dispatch 2: knn (16 lanes/node) + edge, barrier, ewdeg
// d2 bit-exact vs passing rounds: dot = fma(y_i,y_j, round(x_i*x_j));
// d2 = round((sq_i+sq_j) - 2*dot). Key = map(d2bits)<<32 | j (index tie-break).
// 64 nodes/block, 16-lane group per node (aligned within waves). Count-based
// stop (R9/R10-validated, partition-independent, provably exact with 1e-5
// margin >> ~1e-6 Gram noise). Merge: 16 rounds of group-min extraction.
__global__ __launch_bounds__(1024) void knn_ewdeg_kernel(const float4* __restrict__ sorted,
                                                         const unsigned* __restrict__ cstart,
                                                         const float* __restrict__ c,
                                                         int* __restrict__ nbr,
                                                         float* __restrict__ ew,   // d then ew in-place
                                                         unsigned* __restrict__ gmm,
                                                         float* __restrict__ dis,
                                                         unsigned* __restrict__ bctr) {
#pragma clang fp contract(off)
  const int tid = threadIdx.x;
  // ================= Phase A: knn + edge (16 lanes/node) =================
  {
    const int t = blockIdx.x * 64 + (tid >> 4);      // sorted node index
    const int q = tid & 15;                          // group lane
    const float4 me = sorted[t];
    const int myid = (int)__float_as_uint(me.w);
    const float h = 1.0f / GG;                       // exact 2^-6
    int cx = (int)(me.x * GG); cx = cx > GG-1 ? GG-1 : (cx < 0 ? 0 : cx);
    int cy = (int)(me.y * GG); cy = cy > GG-1 ? GG-1 : (cy < 0 ? 0 : cy);

    unsigned long long kd[KK];
#pragma unroll
    for (int m = 0; m < KK; ++m) kd[m] = ~0ull;

    auto process = [&](float4 cand) {
      int j = (int)__float_as_uint(cand.w);
      float xprod = me.x * cand.x;                       // round(x_i*x_j)
      float dot   = __builtin_fmaf(me.y, cand.y, xprod); // BLAS K=2 fma
      float S     = me.z + cand.z;                       // round(sq_i+sq_j)
      float twod  = dot + dot;                           // exact *2
      float d2    = S - twod;                            // one rounding
      unsigned ub = __float_as_uint(d2);
      ub = (ub & 0x80000000u) ? ~ub : (ub | 0x80000000u);
      unsigned long long key = ((unsigned long long)ub << 32) | (unsigned)j;
      if (j != myid && key < kd[KK-1]) {
        unsigned long long ck = key;
#pragma unroll
        for (int m = 0; m < KK; ++m) {
          bool sw = ck < kd[m];
          unsigned long long lo = sw ? ck : kd[m];
          unsigned long long hi = sw ? kd[m] : ck;
          kd[m] = lo; ck = hi;
        }
      }
    };
    auto scanSpan = [&](unsigned p0, unsigned p1) {   // software-pipelined
      unsigned pp = p0 + (unsigned)q;
      if (pp >= p1) return;
      float4 cur = sorted[pp];
      unsigned pn = pp + 16;
      while (pn < p1) {
        float4 nxt = sorted[pn];
        process(cur);
        cur = nxt;
        pn += 16;
      }
      process(cur);
    };
    auto scanRow = [&](int y, int x0, int x1) {
      unsigned p0 = cstart[y*GG + x0];
      unsigned p1 = cstart[y*GG + x1 + 1];
      scanSpan(p0, p1);
    };

    int lxa = cx-2 < 0 ? 0 : cx-2;
    int lxb = cx+2 > GG-1 ? GG-1 : cx+2;
    int lya = cy-2 < 0 ? 0 : cy-2;
    int lyb = cy+2 > GG-1 ? GG-1 : cy+2;
    {
      unsigned rb0[5], rb1[5];
      int nr = lyb - lya + 1;
#pragma unroll
      for (int k = 0; k < 5; ++k) {
        int y = lya + k;
        if (k < nr) {
          rb0[k] = cstart[y*GG + lxa];
          rb1[k] = cstart[y*GG + lxb + 1];
        }
      }
#pragma unroll
      for (int k = 0; k < 5; ++k)
        if (k < nr) scanSpan(rb0[k], rb1[k]);
    }

    int R = 2;
    while (true) {
      bool whole = (lxa <= 0) && (lxb >= GG-1) && (lya <= 0) && (lyb >= GG-1);
      bool done = whole;
      if (!done) {
        float edge = 1e30f;
        if (lxa > 0)    edge = fminf(edge, me.x - (float)lxa * h);
        if (lxb < GG-1) edge = fminf(edge, (float)(lxb+1) * h - me.x);
        if (lya > 0)    edge = fminf(edge, me.y - (float)lya * h);
        if (lyb < GG-1) edge = fminf(edge, (float)(lyb+1) * h - me.y);
        float lim = edge * edge - 1e-5f;             // margin >> Gram noise (~1e-6)
        if (lim > 0.0f) {
          unsigned lb = __float_as_uint(lim) | 0x80000000u;
          int cle = 0;
#pragma unroll
          for (int m = 0; m < KK; ++m) cle += ((unsigned)(kd[m] >> 32) <= lb) ? 1 : 0;
          cle += __shfl_xor(cle, 1, 64);
          cle += __shfl_xor(cle, 2, 64);
          cle += __shfl_xor(cle, 4, 64);
          cle += __shfl_xor(cle, 8, 64);             // sum over 16-lane group
          done = cle >= KK;
        }
      }
      if (done) break;
      ++R;
      int nxa = cx-R < 0 ? 0 : cx-R;
      int nxb = cx+R > GG-1 ? GG-1 : cx+R;
      int nya = cy-R < 0 ? 0 : cy-R;
      int nyb = cy+R > GG-1 ? GG-1 : cy+R;
      if (nya < lya) scanRow(nya, nxa, nxb);
      if (nyb > lyb) scanRow(nyb, nxa, nxb);
      if (nxa < lxa) for (int y = lya; y <= lyb; ++y) scanRow(y, nxa, nxa);
      if (nxb > lxb) for (int y = lya; y <= lyb; ++y) scanRow(y, nxb, nxb);
      lxa = nxa; lxb = nxb; lya = nya; lyb = nyb;
    }

    // merge 16 per-lane lists -> global top-16 (keys unique via j bits)
    unsigned res = 0;
    for (int r = 0; r < KK; ++r) {
      unsigned long long md = kd[0];
      unsigned long long m1 = __shfl_xor(md, 1, 64); md = m1 < md ? m1 : md;
      unsigned long long m2 = __shfl_xor(md, 2, 64); md = m2 < md ? m2 : md;
      unsigned long long m4 = __shfl_xor(md, 4, 64); md = m4 < md ? m4 : md;
      unsigned long long m8 = __shfl_xor(md, 8, 64); md = m8 < md ? m8 : md;
      if (kd[0] == md) {                             // unique winner lane pops
#pragma unroll
        for (int m = 0; m < KK-1; ++m) kd[m] = kd[m+1];
        kd[KK-1] = ~0ull;
      }
      if (q == r) res = (unsigned)(md & 0xFFFFFFFFull);
    }

    // write nbr + edge epilogue (identical ops to passing rounds)
    int j = (int)res;
    nbr[myid*KK + q] = j;
    float dx = me.x - c[2*j];
    float dy = me.y - c[2*j+1];
    float xx = dx * dx;
    float yy = dy * dy;
    float d  = __builtin_sqrtf(xx + yy);
    ew[myid*KK + q] = d;                             // d now, ew after phase B
    unsigned bmin = __float_as_uint(d), bmax = bmin; // d >= 0: bit order == value order
#pragma unroll
    for (int off = 32; off > 0; off >>= 1) {
      unsigned ob = __shfl_xor(bmin, off, 64);
      bmin = bmin < ob ? bmin : ob;
      unsigned oB = __shfl_xor(bmax, off, 64);
      bmax = bmax > oB ? bmax : oB;
    }
    if ((tid & 63) == 0) {
      atomicMin(&gmm[0], bmin);
      atomicMax(&gmm[1], bmax);
    }
  }

  grid_barrier(bctr, NBLK);

  // ================= Phase B: ew + deg + dis =================
  if (tid < 64) {
    int i = blockIdx.x * 64 + tid;                   // 250*64 == NN exactly
    float mx  = __uint_as_float(gmm[1]);
    float rng = mx - __uint_as_float(gmm[0]);
    float deg = 0.0f;                                // edges first, self-loop last
    float4* dp = (float4*)(ew + i*KK);
#pragma unroll
    for (int qq = 0; qq < 4; ++qq) {
      float4 v4 = dp[qq];
      float e0 = (mx - v4.x) / rng;
      float e1 = (mx - v4.y) / rng;
      float e2 = (mx - v4.z) / rng;
      float e3 = (mx - v4.w) / rng;
      deg = deg + e0; deg = deg + e1;
      deg = deg + e2; deg = deg + e3;
      dp[qq] = make_float4(e0, e1, e2, e3);
    }
    deg = deg + 1.0f;                                // self-loop weight 1, added last
    dis[i] = 1.0f / __builtin_sqrtf(deg);            // deg >= 1
  }
}

// ---------------------------------------------------------------- agg1 + relu + gemm2 fused (R10 verbatim)
__global__ __launch_bounds__(256) void agg_gemm2_kernel(const float* __restrict__ xw,
                                                        const int* __restrict__ nbr,
                                                        const float* __restrict__ ew,
                                                        const float* __restrict__ dis,
                                                        const float* __restrict__ b,
                                                        const int* __restrict__ sid,
                                                        const float* __restrict__ w2,
                                                        float* __restrict__ xw2) {
  int wv = threadIdx.x >> 6, lane = threadIdx.x & 63;
  int i = sid[(blockIdx.x << 2) + wv];
  float di = dis[i];
  float acc = 0.0f;
#pragma unroll 4
  for (int k = 0; k < KK; ++k) {
    int s = nbr[i*KK + k];
    float coef = (dis[s] * ew[i*KK + k]) * di;   // (dis[s]*w)*dis[t]
    acc = fmaf(coef, xw[s*HH + lane], acc);
  }
  acc = fmaf(di * di, xw[i*HH + lane], acc);     // self loop last
  float hv = fmaxf(acc + b[lane], 0.0f);         // h1[i][lane]
  float acc2 = 0.0f;
#pragma unroll 16
  for (int k = 0; k < HH; ++k) {
    float hk = __shfl(hv, k, 64);
    acc2 = fmaf(hk, w2[k*HH + lane], acc2);
  }
  xw2[i*HH + lane] = acc2;
}

// ---------------------------------------------------------------- agg2 + relu + fc (R10 verbatim)
__global__ __launch_bounds__(256) void agg_fc_kernel(const float* __restrict__ xw,
                                                     const int* __restrict__ nbr,
                                                     const float* __restrict__ ew,
                                                     const float* __restrict__ dis,
                                                     const float* __restrict__ b,
                                                     const float* __restrict__ wfc,
                                                     const float* __restrict__ bfc,
                                                     const int* __restrict__ sid,
                                                     float* __restrict__ out) {
  int wv = threadIdx.x >> 6, lane = threadIdx.x & 63;
  int i = sid[(blockIdx.x << 2) + wv];
  float di = dis[i];
  float acc = 0.0f;
#pragma unroll 4
  for (int k = 0; k < KK; ++k) {
    int s = nbr[i*KK + k];
    float coef = (dis[s] * ew[i*KK + k]) * di;
    acc = fmaf(coef, xw[s*HH + lane], acc);
  }
  acc = fmaf(di * di, xw[i*HH + lane], acc);
  float v = fmaxf(acc + b[lane], 0.0f);             // h2 feature
  float p = v * wfc[lane];                          // h2 @ Wfc (F_OUT = 1)
#pragma unroll
  for (int off = 32; off > 0; off >>= 1) p = p + __shfl_xor(p, off, 64);
  if (lane == 0) out[i] = p + bfc[0];
}

// ---------------------------------------------------------------- launch
extern "C" void kernel_launch(void* const* d_in, const int* in_sizes, int n_in,
                              void* d_out, int out_size, void* d_ws, size_t ws_size,
                              hipStream_t stream) {
  (void)in_sizes; (void)n_in; (void)out_size; (void)ws_size;
  const float* x   = (const float*)d_in[0];
  const float* c   = (const float*)d_in[1];
  const float* W1  = (const float*)d_in[2];
  const float* b1  = (const float*)d_in[3];
  const float* W2  = (const float*)d_in[4];
  const float* b2  = (const float*)d_in[5];
  const float* Wfc = (const float*)d_in[6];
  const float* bfc = (const float*)d_in[7];
  float* out = (float*)d_out;

  char* ws = (char*)d_ws;
  size_t off = 0;
  auto alloc = [&](size_t bytes) -> void* {
    void* p = ws + off;
    off += (bytes + 255) & ~size_t(255);
    return p;
  };
  float4*   pack   = (float4*)  alloc(NN * sizeof(float4));       // 256 KB
  float4*   sorted = (float4*)  alloc(NN * sizeof(float4));       // 256 KB
  unsigned* cstart = (unsigned*)alloc((NCELL+1) * sizeof(unsigned));
  unsigned* cellid = (unsigned*)alloc(NN * sizeof(unsigned));     // 64 KB
  int*      sid    = (int*)     alloc(NN * sizeof(int));          // 64 KB
  int*      nbr    = (int*)     alloc(NE * sizeof(int));          // 1 MB
  float*    ew     = (float*)   alloc(NE * sizeof(float));        // 1 MB (d then ew in-place)
  float*    dis    = (float*)   alloc(NN * sizeof(float));        // 64 KB
  unsigned* gmm    = (unsigned*)alloc(2 * sizeof(unsigned));
  unsigned* bctr   = (unsigned*)alloc(sizeof(unsigned));
  float*    xw1    = (float*)   alloc(NN * HH * sizeof(float));   // 4 MB
  float*    xw2    = (float*)   alloc(NN * HH * sizeof(float));   // 4 MB

  binsort_gemm1_kernel<<<251, 1024, 0, stream>>>(c, x, W1, pack, cellid, cstart,
                                                 sorted, sid, xw1, gmm, bctr);
  knn_ewdeg_kernel    <<<NBLK, 1024, 0, stream>>>(sorted, cstart, c, nbr, ew, gmm,
                                                  dis, bctr);
  agg_gemm2_kernel    <<<NN/4, 256, 0, stream>>>(xw1, nbr, ew, dis, b1, sid, W2, xw2);
  agg_fc_kernel       <<<NN/4, 256, 0, stream>>>(xw2, nbr, ew, dis, b2, Wfc, bfc, sid, out);
}

// Round 13
// 200.490 us; speedup vs baseline: 1.5634x; 1.2948x over previous
//
#include <hip/hip_runtime.h>
#include <cstdint>

#define NN 16000
#define KK 16
#define FIN 32
#define HH 64
#define NE (NN*KK)
#define GG 64
#define NCELL (GG*GG)
#define NBLK 250            // knn/ewdeg grid: 250 blocks <= 256 CUs -> co-resident

// ---------------------------------------------------------------- grid barrier (device-scope)
__device__ __forceinline__ void grid_barrier(unsigned* ctr, unsigned target) {
  __syncthreads();
  if (threadIdx.x == 0) {
    __threadfence();                               // release all prior writes
    __hip_atomic_fetch_add(ctr, 1u, __ATOMIC_ACQ_REL, __HIP_MEMORY_SCOPE_AGENT);
    unsigned spins = 0;
    while (__hip_atomic_load(ctr, __ATOMIC_ACQUIRE, __HIP_MEMORY_SCOPE_AGENT) < target) {
      __builtin_amdgcn_s_sleep(8);
      if (++spins > 200000000u) break;             // fail loud, never hang
    }
    __threadfence();                               // acquire: see others' writes
  }
  __syncthreads();
}

// ---------------------------------------------------------------- dispatch 1: binsort (block 0) + gemm1 (blocks 1..250)
// binsort: pack[i]=(x,y,sq,idxbits), sq = round(x^2)+round(y^2) UNFUSED (np c*c+sum);
// LDS histogram -> wave-shuffle scan -> LDS-cursor scatter. Within-cell order is
// arbitrary but all downstream outputs are order-invariant (unique keys, per-node math).
__global__ __launch_bounds__(1024) void binsort_gemm1_kernel(const float* __restrict__ c,
                                                             const float* __restrict__ x,
                                                             const float* __restrict__ w1,
                                                             float4* __restrict__ pack,
                                                             unsigned* __restrict__ cellid,
                                                             unsigned* __restrict__ cstart,
                                                             float4* __restrict__ sorted,
                                                             int* __restrict__ sid,
                                                             float* __restrict__ xw1,
                                                             unsigned* __restrict__ gmm,
                                                             unsigned* __restrict__ bctr) {
#pragma clang fp contract(off)
  const int tid = threadIdx.x;
  if (blockIdx.x > 0) {
    // ---------------- gemm1: xw1 = x @ W1 (KIN=32), 4 features/thread
    int gid = (int)(blockIdx.x - 1) * 1024 + tid;   // 0..255999
    int i = gid >> 4, fq = gid & 15;
    const float4* ar = (const float4*)(x + i * FIN);
    float4 A[FIN/4];
#pragma unroll
    for (int qq = 0; qq < FIN/4; ++qq) A[qq] = ar[qq];
    float4 acc = make_float4(0.f, 0.f, 0.f, 0.f);
#pragma unroll
    for (int k = 0; k < FIN; ++k) {
      float av = ((const float*)A)[k];
      float4 wv4 = *(const float4*)(w1 + k*HH + 4*fq);
      acc.x = fmaf(av, wv4.x, acc.x);
      acc.y = fmaf(av, wv4.y, acc.y);
      acc.z = fmaf(av, wv4.z, acc.z);
      acc.w = fmaf(av, wv4.w, acc.w);
    }
    *(float4*)(xw1 + i*HH + 4*fq) = acc;
    return;
  }
  // ---------------- binsort (single block, 1024 threads)
  __shared__ unsigned hist[NCELL];                  // 16 KB
  __shared__ unsigned wsum[16];
  const int lane = tid & 63, wv = tid >> 6;
  if (tid == 0) { gmm[0] = 0x7F800000u; gmm[1] = 0u; *bctr = 0u; }
  for (int j = tid; j < NCELL; j += 1024) hist[j] = 0u;
  __syncthreads();
  for (int i = tid; i < NN; i += 1024) {
    float xv = c[2*i], yv = c[2*i+1];
    float xx = xv * xv;                             // round(x^2) (no fma: contract off)
    float yy = yv * yv;                             // round(y^2)
    float sq = xx + yy;                             // round(xx+yy)
    pack[i] = make_float4(xv, yv, sq, __uint_as_float((unsigned)i));
    int cx = (int)(xv * GG); cx = cx > GG-1 ? GG-1 : (cx < 0 ? 0 : cx);
    int cy = (int)(yv * GG); cy = cy > GG-1 ? GG-1 : (cy < 0 ? 0 : cy);
    unsigned cell = (unsigned)(cy * GG + cx);
    cellid[i] = cell;
    atomicAdd(&hist[cell], 1u);
  }
  __syncthreads();
  unsigned h0 = hist[tid*4+0], h1 = hist[tid*4+1], h2 = hist[tid*4+2], h3 = hist[tid*4+3];
  unsigned s = h0 + h1 + h2 + h3;
  unsigned v = s;
#pragma unroll
  for (int off = 1; off < 64; off <<= 1) {
    unsigned u = __shfl_up(v, off, 64);
    if (lane >= off) v += u;
  }
  if (lane == 63) wsum[wv] = v;
  __syncthreads();
  if (wv == 0) {
    unsigned t = (lane < 16) ? wsum[lane] : 0u;
    unsigned vv = t;
#pragma unroll
    for (int off = 1; off < 16; off <<= 1) {
      unsigned u = __shfl_up(vv, off, 64);
      if (lane >= off) vv += u;
    }
    if (lane < 16) wsum[lane] = vv - t;             // exclusive
  }
  __syncthreads();
  unsigned b = wsum[wv] + v - s;
  unsigned cur0 = b;             cstart[tid*4+0] = b; b += h0;
  unsigned cur1 = b;             cstart[tid*4+1] = b; b += h1;
  unsigned cur2 = b;             cstart[tid*4+2] = b; b += h2;
  unsigned cur3 = b;             cstart[tid*4+3] = b; b += h3;
  hist[tid*4+0] = cur0; hist[tid*4+1] = cur1; hist[tid*4+2] = cur2; hist[tid*4+3] = cur3;
  if (tid == 1023) cstart[NCELL] = b;               // == NN
  __syncthreads();
  for (int i = tid; i < NN; i += 1024) {
    unsigned p = atomicAdd(&hist[cellid[i]], 1u);
    sorted[p] = pack[i];
    sid[p] = i;
  }
}

// ---------------------------------------------------------------- dispatch 2: knn (R10-exact 4-lane) + edge, barrier, ewdeg
// 256-thread blocks (VGPR-unconstrained -> no spills; R12's 1024-thread variant
// spilled kd[16] to scratch: WRITE_SIZE 7.3MB, 123us). knn d2 bit-exact:
//   dot = fma(y_i,y_j, round(x_i*x_j)); d2 = round((sq_i+sq_j) - 2*dot)
// Key = map(d2bits)<<32 | j. Pipelined span scan; count-based stop (exact).
__global__ __launch_bounds__(256) void knn_ewdeg_kernel(const float4* __restrict__ sorted,
                                                        const unsigned* __restrict__ cstart,
                                                        const float* __restrict__ c,
                                                        int* __restrict__ nbr,
                                                        float* __restrict__ ew,   // d then ew in-place
                                                        unsigned* __restrict__ gmm,
                                                        float* __restrict__ dis,
                                                        unsigned* __restrict__ bctr) {
#pragma clang fp contract(off)
  const int tid = threadIdx.x;
  const int lane = tid & 63;

  // ================= Phase A: knn + edge (R10 verbatim) =================
  {
    const int g = blockIdx.x * 256 + tid;
    const int t = g >> 2;                            // sorted node index
    const int q = g & 3;                             // quad lane
    const float4 me = sorted[t];
    const int myid = (int)__float_as_uint(me.w);
    const float h = 1.0f / GG;                       // exact 2^-6
    int cx = (int)(me.x * GG); cx = cx > GG-1 ? GG-1 : (cx < 0 ? 0 : cx);
    int cy = (int)(me.y * GG); cy = cy > GG-1 ? GG-1 : (cy < 0 ? 0 : cy);

    unsigned long long kd[KK];
#pragma unroll
    for (int m = 0; m < KK; ++m) kd[m] = ~0ull;

    auto process = [&](float4 cand) {
      int j = (int)__float_as_uint(cand.w);
      float xprod = me.x * cand.x;                       // round(x_i*x_j)
      float dot   = __builtin_fmaf(me.y, cand.y, xprod); // BLAS K=2 fma
      float S     = me.z + cand.z;                       // round(sq_i+sq_j)
      float twod  = dot + dot;                           // exact *2
      float d2    = S - twod;                            // one rounding
      unsigned ub = __float_as_uint(d2);
      ub = (ub & 0x80000000u) ? ~ub : (ub | 0x80000000u);
      unsigned long long key = ((unsigned long long)ub << 32) | (unsigned)j;
      if (j != myid && key < kd[KK-1]) {
        unsigned long long ck = key;
#pragma unroll
        for (int m = 0; m < KK; ++m) {
          bool sw = ck < kd[m];
          unsigned long long lo = sw ? ck : kd[m];
          unsigned long long hi = sw ? kd[m] : ck;
          kd[m] = lo; ck = hi;
        }
      }
    };
    auto scanSpan = [&](unsigned p0, unsigned p1) {   // software-pipelined
      unsigned pp = p0 + (unsigned)q;
      if (pp >= p1) return;
      float4 cur = sorted[pp];
      unsigned pn = pp + 4;
      while (pn < p1) {
        float4 nxt = sorted[pn];
        process(cur);
        cur = nxt;
        pn += 4;
      }
      process(cur);
    };
    auto scanRow = [&](int y, int x0, int x1) {
      unsigned p0 = cstart[y*GG + x0];
      unsigned p1 = cstart[y*GG + x1 + 1];
      scanSpan(p0, p1);
    };

    int lxa = cx-2 < 0 ? 0 : cx-2;
    int lxb = cx+2 > GG-1 ? GG-1 : cx+2;
    int lya = cy-2 < 0 ? 0 : cy-2;
    int lyb = cy+2 > GG-1 ? GG-1 : cy+2;
    {
      unsigned rb0[5], rb1[5];
      int nr = lyb - lya + 1;
#pragma unroll
      for (int k = 0; k < 5; ++k) {
        int y = lya + k;
        if (k < nr) {
          rb0[k] = cstart[y*GG + lxa];
          rb1[k] = cstart[y*GG + lxb + 1];
        }
      }
#pragma unroll
      for (int k = 0; k < 5; ++k)
        if (k < nr) scanSpan(rb0[k], rb1[k]);
    }

    int R = 2;
    while (true) {
      bool whole = (lxa <= 0) && (lxb >= GG-1) && (lya <= 0) && (lyb >= GG-1);
      bool done = whole;
      if (!done) {
        float edge = 1e30f;
        if (lxa > 0)    edge = fminf(edge, me.x - (float)lxa * h);
        if (lxb < GG-1) edge = fminf(edge, (float)(lxb+1) * h - me.x);
        if (lya > 0)    edge = fminf(edge, me.y - (float)lya * h);
        if (lyb < GG-1) edge = fminf(edge, (float)(lyb+1) * h - me.y);
        float lim = edge * edge - 1e-5f;             // margin >> Gram noise (~1e-6)
        if (lim > 0.0f) {
          unsigned lb = __float_as_uint(lim) | 0x80000000u;
          int cle = 0;
#pragma unroll
          for (int m = 0; m < KK; ++m) cle += ((unsigned)(kd[m] >> 32) <= lb) ? 1 : 0;
          cle += __shfl_xor(cle, 1, 64);
          cle += __shfl_xor(cle, 2, 64);
          done = cle >= KK;
        }
      }
      if (done) break;
      ++R;
      int nxa = cx-R < 0 ? 0 : cx-R;
      int nxb = cx+R > GG-1 ? GG-1 : cx+R;
      int nya = cy-R < 0 ? 0 : cy-R;
      int nyb = cy+R > GG-1 ? GG-1 : cy+R;
      if (nya < lya) scanRow(nya, nxa, nxb);
      if (nyb > lyb) scanRow(nyb, nxa, nxb);
      if (nxa < lxa) for (int y = lya; y <= lyb; ++y) scanRow(y, nxa, nxa);
      if (nxb > lxb) for (int y = lya; y <= lyb; ++y) scanRow(y, nxb, nxb);
      lxa = nxa; lxb = nxb; lya = nya; lyb = nyb;
    }

    unsigned res[4];
    for (int r = 0; r < KK; ++r) {
      unsigned long long md = kd[0];
      unsigned long long m1 = __shfl_xor(md, 1, 64); md = m1 < md ? m1 : md;
      unsigned long long m2 = __shfl_xor(md, 2, 64); md = m2 < md ? m2 : md;
      if (kd[0] == md) {                             // unique winner lane pops
#pragma unroll
        for (int m = 0; m < KK-1; ++m) kd[m] = kd[m+1];
        kd[KK-1] = ~0ull;
      }
      if ((r >> 2) == q) res[r & 3] = (unsigned)(md & 0xFFFFFFFFull);
    }

    int4 w4; w4.x = (int)res[0]; w4.y = (int)res[1]; w4.z = (int)res[2]; w4.w = (int)res[3];
    *(int4*)(nbr + myid*KK + 4*q) = w4;
    unsigned bmin = 0xFFFFFFFFu, bmax = 0u;
#pragma unroll
    for (int e = 0; e < 4; ++e) {
      int j = (int)res[e];
      float dx = me.x - c[2*j];
      float dy = me.y - c[2*j+1];
      float xx = dx * dx;
      float yy = dy * dy;
      float d  = __builtin_sqrtf(xx + yy);
      ew[myid*KK + 4*q + e] = d;                     // d now, ew after phase B
      unsigned bb = __float_as_uint(d);
      bmin = bmin < bb ? bmin : bb;
      bmax = bmax > bb ? bmax : bb;
    }
#pragma unroll
    for (int off = 32; off > 0; off >>= 1) {
      unsigned ob = __shfl_xor(bmin, off, 64);
      bmin = bmin < ob ? bmin : ob;
      unsigned oB = __shfl_xor(bmax, off, 64);
      bmax = bmax > oB ? bmax : oB;
    }
    if (lane == 0) {
      atomicMin(&gmm[0], bmin);
      atomicMax(&gmm[1], bmax);
    }
  }

  grid_barrier(bctr, NBLK);

  // ================= Phase B: ew + deg + dis =================
  if (tid < 64) {
    int i = blockIdx.x * 64 + tid;                   // 250*64 == NN exactly
    float mx  = __uint_as_float(gmm[1]);
    float rng = mx - __uint_as_float(gmm[0]);
    float deg = 0.0f;                                // edges first, self-loop last
    float4* dp = (float4*)(ew + i*KK);
#pragma unroll
    for (int qq = 0; qq < 4; ++qq) {
      float4 v4 = dp[qq];
      float e0 = (mx - v4.x) / rng;
      float e1 = (mx - v4.y) / rng;
      float e2 = (mx - v4.z) / rng;
      float e3 = (mx - v4.w) / rng;
      deg = deg + e0; deg = deg + e1;
      deg = deg + e2; deg = deg + e3;
      dp[qq] = make_float4(e0, e1, e2, e3);
    }
    deg = deg + 1.0f;                                // self-loop weight 1, added last
    dis[i] = 1.0f / __builtin_sqrtf(deg);            // deg >= 1
  }
}

// ---------------------------------------------------------------- agg1 + relu + gemm2 fused (R10 verbatim)
__global__ __launch_bounds__(256) void agg_gemm2_kernel(const float* __restrict__ xw,
                                                        const int* __restrict__ nbr,
                                                        const float* __restrict__ ew,
                                                        const float* __restrict__ dis,
                                                        const float* __restrict__ b,
                                                        const int* __restrict__ sid,
                                                        const float* __restrict__ w2,
                                                        float* __restrict__ xw2) {
  int wv = threadIdx.x >> 6, lane = threadIdx.x & 63;
  int i = sid[(blockIdx.x << 2) + wv];
  float di = dis[i];
  float acc = 0.0f;
#pragma unroll 4
  for (int k = 0; k < KK; ++k) {
    int s = nbr[i*KK + k];
    float coef = (dis[s] * ew[i*KK + k]) * di;   // (dis[s]*w)*dis[t]
    acc = fmaf(coef, xw[s*HH + lane], acc);
  }
  acc = fmaf(di * di, xw[i*HH + lane], acc);     // self loop last
  float hv = fmaxf(acc + b[lane], 0.0f);         // h1[i][lane]
  float acc2 = 0.0f;
#pragma unroll 16
  for (int k = 0; k < HH; ++k) {
    float hk = __shfl(hv, k, 64);
    acc2 = fmaf(hk, w2[k*HH + lane], acc2);
  }
  xw2[i*HH + lane] = acc2;
}

// ---------------------------------------------------------------- agg2 + relu + fc (R10 verbatim)
__global__ __launch_bounds__(256) void agg_fc_kernel(const float* __restrict__ xw,
                                                     const int* __restrict__ nbr,
                                                     const float* __restrict__ ew,
                                                     const float* __restrict__ dis,
                                                     const float* __restrict__ b,
                                                     const float* __restrict__ wfc,
                                                     const float* __restrict__ bfc,
                                                     const int* __restrict__ sid,
                                                     float* __restrict__ out) {
  int wv = threadIdx.x >> 6, lane = threadIdx.x & 63;
  int i = sid[(blockIdx.x << 2) + wv];
  float di = dis[i];
  float acc = 0.0f;
#pragma unroll 4
  for (int k = 0; k < KK; ++k) {
    int s = nbr[i*KK + k];
    float coef = (dis[s] * ew[i*KK + k]) * di;
    acc = fmaf(coef, xw[s*HH + lane], acc);
  }
  acc = fmaf(di * di, xw[i*HH + lane], acc);
  float v = fmaxf(acc + b[lane], 0.0f);             // h2 feature
  float p = v * wfc[lane];                          // h2 @ Wfc (F_OUT = 1)
#pragma unroll
  for (int off = 32; off > 0; off >>= 1) p = p + __shfl_xor(p, off, 64);
  if (lane == 0) out[i] = p + bfc[0];
}

// ---------------------------------------------------------------- launch
extern "C" void kernel_launch(void* const* d_in, const int* in_sizes, int n_in,
                              void* d_out, int out_size, void* d_ws, size_t ws_size,
                              hipStream_t stream) {
  (void)in_sizes; (void)n_in; (void)out_size; (void)ws_size;
  const float* x   = (const float*)d_in[0];
  const float* c   = (const float*)d_in[1];
  const float* W1  = (const float*)d_in[2];
  const float* b1  = (const float*)d_in[3];
  const float* W2  = (const float*)d_in[4];
  const float* b2  = (const float*)d_in[5];
  const float* Wfc = (const float*)d_in[6];
  const float* bfc = (const float*)d_in[7];
  float* out = (float*)d_out;

  char* ws = (char*)d_ws;
  size_t off = 0;
  auto alloc = [&](size_t bytes) -> void* {
    void* p = ws + off;
    off += (bytes + 255) & ~size_t(255);
    return p;
  };
  float4*   pack   = (float4*)  alloc(NN * sizeof(float4));       // 256 KB
  float4*   sorted = (float4*)  alloc(NN * sizeof(float4));       // 256 KB
  unsigned* cstart = (unsigned*)alloc((NCELL+1) * sizeof(unsigned));
  unsigned* cellid = (unsigned*)alloc(NN * sizeof(unsigned));     // 64 KB
  int*      sid    = (int*)     alloc(NN * sizeof(int));          // 64 KB
  int*      nbr    = (int*)     alloc(NE * sizeof(int));          // 1 MB
  float*    ew     = (float*)   alloc(NE * sizeof(float));        // 1 MB (d then ew in-place)
  float*    dis    = (float*)   alloc(NN * sizeof(float));        // 64 KB
  unsigned* gmm    = (unsigned*)alloc(2 * sizeof(unsigned));
  unsigned* bctr   = (unsigned*)alloc(sizeof(unsigned));
  float*    xw1    = (float*)   alloc(NN * HH * sizeof(float));   // 4 MB
  float*    xw2    = (float*)   alloc(NN * HH * sizeof(float));   // 4 MB

  binsort_gemm1_kernel<<<251, 1024, 0, stream>>>(c, x, W1, pack, cellid, cstart,
                                                 sorted, sid, xw1, gmm, bctr);
  knn_ewdeg_kernel    <<<NBLK, 256, 0, stream>>>(sorted, cstart, c, nbr, ew, gmm,
                                                 dis, bctr);
  agg_gemm2_kernel    <<<NN/4, 256, 0, stream>>>(xw1, nbr, ew, dis, b1, sid, W2, xw2);
  agg_fc_kernel       <<<NN/4, 256, 0, stream>>>(xw2, nbr, ew, dis, b2, Wfc, bfc, sid, out);
}

// Round 14
// 182.949 us; speedup vs baseline: 1.7133x; 1.0959x over previous
//
#include <hip/hip_runtime.h>
#include <cstdint>

#define NN 16000
#define KK 16
#define FIN 32
#define HH 64
#define NE (NN*KK)
#define GG 64
#define NCELL (GG*GG)
#define NPC 63              // prep_count blocks (63*256 = 16128 >= NN)
#define G1B 1000            // gemm1 blocks

// ---------------------------------------------------------------- dispatch 2: prep_count (blocks 0..62) + gemm1 (63..1062)
// prep: pack[i]=(x,y,sq,idxbits), sq = round(x^2)+round(y^2) UNFUSED (np c*c+sum).
__global__ __launch_bounds__(256) void prep_count_gemm1_kernel(const float* __restrict__ c,
                                                               const float* __restrict__ x,
                                                               const float* __restrict__ w1,
                                                               float4* __restrict__ pack,
                                                               unsigned* __restrict__ cellid,
                                                               unsigned* __restrict__ cnt,
                                                               unsigned* __restrict__ gmm,
                                                               float* __restrict__ xw1) {
#pragma clang fp contract(off)
  const int tid = threadIdx.x;
  if (blockIdx.x >= NPC) {
    // ---------------- gemm1: xw1 = x @ W1 (KIN=32), 4 features/thread (R10 verbatim)
    int gid = (int)(blockIdx.x - NPC) * 256 + tid;   // 0..255999
    int i = gid >> 4, fq = gid & 15;
    const float4* ar = (const float4*)(x + i * FIN);
    float4 A[FIN/4];
#pragma unroll
    for (int qq = 0; qq < FIN/4; ++qq) A[qq] = ar[qq];
    float4 acc = make_float4(0.f, 0.f, 0.f, 0.f);
#pragma unroll
    for (int k = 0; k < FIN; ++k) {
      float av = ((const float*)A)[k];
      float4 wv4 = *(const float4*)(w1 + k*HH + 4*fq);
      acc.x = fmaf(av, wv4.x, acc.x);
      acc.y = fmaf(av, wv4.y, acc.y);
      acc.z = fmaf(av, wv4.z, acc.z);
      acc.w = fmaf(av, wv4.w, acc.w);
    }
    *(float4*)(xw1 + i*HH + 4*fq) = acc;
    return;
  }
  // ---------------- prep + count (R10 verbatim math)
  int i = (int)blockIdx.x * 256 + tid;
  if (i == 0) { gmm[0] = 0x7F800000u; gmm[1] = 0u; }  // min=+inf bits, max=0 (d>=0)
  if (i >= NN) return;
  float xv = c[2*i], yv = c[2*i+1];
  float xx = xv * xv;            // round(x^2)  (no fma: contract off)
  float yy = yv * yv;            // round(y^2)
  float sq = xx + yy;            // round(xx+yy)
  pack[i] = make_float4(xv, yv, sq, __uint_as_float((unsigned)i));
  int cx = (int)(xv * GG); cx = cx > GG-1 ? GG-1 : (cx < 0 ? 0 : cx);
  int cy = (int)(yv * GG); cy = cy > GG-1 ? GG-1 : (cy < 0 ? 0 : cy);
  unsigned cell = (unsigned)(cy * GG + cx);
  cellid[i] = cell;
  atomicAdd(&cnt[cell], 1u);
}

// ---------------------------------------------------------------- dispatch 3: scan (block 63) + scatter (blocks 0..62)
// Single-producer sync: block 63 scans then release-stores flag; scatter blocks
// poll (thread 0, acquire) then scatter via device atomics (atomics bypass L1,
// so cursor values are always coherent). 64 blocks always co-resident on 256 CUs.
__global__ __launch_bounds__(256) void scan_scatter_kernel(const unsigned* __restrict__ cnt,
                                                           unsigned* __restrict__ cstart,
                                                           unsigned* __restrict__ cursor,
                                                           const float4* __restrict__ pack,
                                                           const unsigned* __restrict__ cellid,
                                                           float4* __restrict__ sorted,
                                                           int* __restrict__ sid,
                                                           unsigned* __restrict__ flag) {
  const int tid = threadIdx.x;
  if (blockIdx.x == 63) {
    // ---- scan: 16 cells/thread, 256 threads = 4096 cells
    const int lane = tid & 63, wv = tid >> 6;
    __shared__ unsigned wsum[4];
    unsigned loc[16];
    unsigned tsum = 0;
#pragma unroll
    for (int j = 0; j < 16; ++j) { loc[j] = cnt[tid*16 + j]; tsum += loc[j]; }
    unsigned v = tsum;
#pragma unroll
    for (int off = 1; off < 64; off <<= 1) {
      unsigned u = __shfl_up(v, off, 64);
      if (lane >= off) v += u;
    }
    if (lane == 63) wsum[wv] = v;
    __syncthreads();
    if (tid == 0) {
      unsigned run = 0;
#pragma unroll
      for (int w = 0; w < 4; ++w) { unsigned t = wsum[w]; wsum[w] = run; run += t; }
    }
    __syncthreads();
    unsigned b = wsum[wv] + v - tsum;              // exclusive prefix of this thread's cells
#pragma unroll
    for (int j = 0; j < 16; ++j) {
      cstart[tid*16 + j] = b; cursor[tid*16 + j] = b; b += loc[j];
    }
    if (tid == 255) cstart[NCELL] = b;             // == NN
    __syncthreads();                               // all scan writes issued
    if (tid == 0) {
      __threadfence();                             // publish (release)
      __hip_atomic_store(flag, 1u, __ATOMIC_RELEASE, __HIP_MEMORY_SCOPE_AGENT);
    }
    return;
  }
  // ---- scatter blocks: preload own element, poll, scatter
  int i = (int)blockIdx.x * 256 + tid;
  bool have = i < NN;
  float4 v4 = make_float4(0.f, 0.f, 0.f, 0.f);
  unsigned cell = 0;
  if (have) { v4 = pack[i]; cell = cellid[i]; }
  if (tid == 0) {
    unsigned spins = 0;
    while (__hip_atomic_load(flag, __ATOMIC_ACQUIRE, __HIP_MEMORY_SCOPE_AGENT) == 0u) {
      __builtin_amdgcn_s_sleep(8);
      if (++spins > 100000000u) break;             // fail loud, never hang
    }
  }
  __syncthreads();
  if (have) {
    unsigned p = atomicAdd(&cursor[cell], 1u);     // device atomic: coherent
    sorted[p] = v4;
    sid[p] = i;
  }
}

// ---------------------------------------------------------------- dispatch 4: knn (R10-exact) + edge-d + sumd epilogue
// d2 bit-exact vs passing rounds: dot = fma(y_i,y_j, round(x_i*x_j));
// d2 = round((sq_i+sq_j) - 2*dot). Key = map(d2bits)<<32 | j (index tie-break).
// Pipelined span scan; count-based stop (exact, 1e-5 margin >> ~1e-6 Gram noise).
// Epilogue: d per edge (same ops as passing rounds) + per-node sumd (quad tree sum).
__global__ __launch_bounds__(256) void knn_kernel(const float4* __restrict__ sorted,
                                                  const unsigned* __restrict__ cstart,
                                                  const float* __restrict__ c,
                                                  int* __restrict__ nbr,
                                                  float* __restrict__ de,
                                                  float* __restrict__ sumd,
                                                  unsigned* __restrict__ gmm) {
#pragma clang fp contract(off)
  const int tid = threadIdx.x;
  const int lane = tid & 63;
  const int g = blockIdx.x * 256 + tid;
  const int t = g >> 2;                            // sorted node index
  const int q = g & 3;                             // quad lane
  const float4 me = sorted[t];
  const int myid = (int)__float_as_uint(me.w);
  const float h = 1.0f / GG;                       // exact 2^-6
  int cx = (int)(me.x * GG); cx = cx > GG-1 ? GG-1 : (cx < 0 ? 0 : cx);
  int cy = (int)(me.y * GG); cy = cy > GG-1 ? GG-1 : (cy < 0 ? 0 : cy);

  unsigned long long kd[KK];
#pragma unroll
  for (int m = 0; m < KK; ++m) kd[m] = ~0ull;

  auto process = [&](float4 cand) {
    int j = (int)__float_as_uint(cand.w);
    float xprod = me.x * cand.x;                       // round(x_i*x_j)
    float dot   = __builtin_fmaf(me.y, cand.y, xprod); // BLAS K=2 fma
    float S     = me.z + cand.z;                       // round(sq_i+sq_j)
    float twod  = dot + dot;                           // exact *2
    float d2    = S - twod;                            // one rounding
    unsigned ub = __float_as_uint(d2);
    ub = (ub & 0x80000000u) ? ~ub : (ub | 0x80000000u);
    unsigned long long key = ((unsigned long long)ub << 32) | (unsigned)j;
    if (j != myid && key < kd[KK-1]) {
      unsigned long long ck = key;
#pragma unroll
      for (int m = 0; m < KK; ++m) {
        bool sw = ck < kd[m];
        unsigned long long lo = sw ? ck : kd[m];
        unsigned long long hi = sw ? kd[m] : ck;
        kd[m] = lo; ck = hi;
      }
    }
  };
  auto scanSpan = [&](unsigned p0, unsigned p1) {   // software-pipelined
    unsigned pp = p0 + (unsigned)q;
    if (pp >= p1) return;
    float4 cur = sorted[pp];
    unsigned pn = pp + 4;
    while (pn < p1) {
      float4 nxt = sorted[pn];
      process(cur);
      cur = nxt;
      pn += 4;
    }
    process(cur);
  };
  auto scanRow = [&](int y, int x0, int x1) {
    unsigned p0 = cstart[y*GG + x0];
    unsigned p1 = cstart[y*GG + x1 + 1];
    scanSpan(p0, p1);
  };

  int lxa = cx-2 < 0 ? 0 : cx-2;
  int lxb = cx+2 > GG-1 ? GG-1 : cx+2;
  int lya = cy-2 < 0 ? 0 : cy-2;
  int lyb = cy+2 > GG-1 ? GG-1 : cy+2;
  {
    unsigned rb0[5], rb1[5];
    int nr = lyb - lya + 1;
#pragma unroll
    for (int k = 0; k < 5; ++k) {
      int y = lya + k;
      if (k < nr) {
        rb0[k] = cstart[y*GG + lxa];
        rb1[k] = cstart[y*GG + lxb + 1];
      }
    }
#pragma unroll
    for (int k = 0; k < 5; ++k)
      if (k < nr) scanSpan(rb0[k], rb1[k]);
  }

  int R = 2;
  while (true) {
    bool whole = (lxa <= 0) && (lxb >= GG-1) && (lya <= 0) && (lyb >= GG-1);
    bool done = whole;
    if (!done) {
      float edge = 1e30f;
      if (lxa > 0)    edge = fminf(edge, me.x - (float)lxa * h);
      if (lxb < GG-1) edge = fminf(edge, (float)(lxb+1) * h - me.x);
      if (lya > 0)    edge = fminf(edge, me.y - (float)lya * h);
      if (lyb < GG-1) edge = fminf(edge, (float)(lyb+1) * h - me.y);
      float lim = edge * edge - 1e-5f;             // margin >> Gram noise (~1e-6)
      if (lim > 0.0f) {
        unsigned lb = __float_as_uint(lim) | 0x80000000u;
        int cle = 0;
#pragma unroll
        for (int m = 0; m < KK; ++m) cle += ((unsigned)(kd[m] >> 32) <= lb) ? 1 : 0;
        cle += __shfl_xor(cle, 1, 64);
        cle += __shfl_xor(cle, 2, 64);
        done = cle >= KK;
      }
    }
    if (done) break;
    ++R;
    int nxa = cx-R < 0 ? 0 : cx-R;
    int nxb = cx+R > GG-1 ? GG-1 : cx+R;
    int nya = cy-R < 0 ? 0 : cy-R;
    int nyb = cy+R > GG-1 ? GG-1 : cy+R;
    if (nya < lya) scanRow(nya, nxa, nxb);
    if (nyb > lyb) scanRow(nyb, nxa, nxb);
    if (nxa < lxa) for (int y = lya; y <= lyb; ++y) scanRow(y, nxa, nxa);
    if (nxb > lxb) for (int y = lya; y <= lyb; ++y) scanRow(y, nxb, nxb);
    lxa = nxa; lxb = nxb; lya = nya; lyb = nyb;
  }

  unsigned res[4];
  for (int r = 0; r < KK; ++r) {
    unsigned long long md = kd[0];
    unsigned long long m1 = __shfl_xor(md, 1, 64); md = m1 < md ? m1 : md;
    unsigned long long m2 = __shfl_xor(md, 2, 64); md = m2 < md ? m2 : md;
    if (kd[0] == md) {                             // unique winner lane pops
#pragma unroll
      for (int m = 0; m < KK-1; ++m) kd[m] = kd[m+1];
      kd[KK-1] = ~0ull;
    }
    if ((r >> 2) == q) res[r & 3] = (unsigned)(md & 0xFFFFFFFFull);
  }

  int4 w4; w4.x = (int)res[0]; w4.y = (int)res[1]; w4.z = (int)res[2]; w4.w = (int)res[3];
  *(int4*)(nbr + myid*KK + 4*q) = w4;
  unsigned bmin = 0xFFFFFFFFu, bmax = 0u;
  float qsum = 0.0f;
#pragma unroll
  for (int e = 0; e < 4; ++e) {
    int j = (int)res[e];
    float dx = me.x - c[2*j];
    float dy = me.y - c[2*j+1];
    float xx = dx * dx;
    float yy = dy * dy;
    float d  = __builtin_sqrtf(xx + yy);
    de[myid*KK + 4*q + e] = d;
    qsum = qsum + d;                               // ascending-e local sum
    unsigned bb = __float_as_uint(d);
    bmin = bmin < bb ? bmin : bb;
    bmax = bmax > bb ? bmax : bb;
  }
  // deterministic quad tree-sum of the node's 16 d values
  qsum = qsum + __shfl_xor(qsum, 1, 64);
  qsum = qsum + __shfl_xor(qsum, 2, 64);
  if (q == 0) sumd[myid] = qsum;
#pragma unroll
  for (int off = 32; off > 0; off >>= 1) {
    unsigned ob = __shfl_xor(bmin, off, 64);
    bmin = bmin < ob ? bmin : ob;
    unsigned oB = __shfl_xor(bmax, off, 64);
    bmax = bmax > oB ? bmax : oB;
  }
  if (lane == 0) {
    atomicMin(&gmm[0], bmin);
    atomicMax(&gmm[1], bmax);
  }
}

// ---------------------------------------------------------------- agg1 + relu + gemm2, inline ew/dis
// dis(n) = 1/sqrt(1 + (16*mx - sumd[n])/rng): deg rounding differs from the
// sequential reference by ~1e-6 relative (continuous path only -> ~1e-5 output).
__global__ __launch_bounds__(256) void agg_gemm2_kernel(const float* __restrict__ xw,
                                                        const int* __restrict__ nbr,
                                                        const float* __restrict__ de,
                                                        const float* __restrict__ sumd,
                                                        const unsigned* __restrict__ gmm,
                                                        const float* __restrict__ b,
                                                        const int* __restrict__ sid,
                                                        const float* __restrict__ w2,
                                                        float* __restrict__ xw2) {
#pragma clang fp contract(off)
  int wv = threadIdx.x >> 6, lane = threadIdx.x & 63;
  int i = sid[(blockIdx.x << 2) + wv];
  float mx  = __uint_as_float(gmm[1]);
  float rng = mx - __uint_as_float(gmm[0]);
  float s16 = 16.0f * mx;                          // exact (pow2 scale)
  auto disof = [&](int n) {
    float deg = 1.0f + (s16 - sumd[n]) / rng;
    return 1.0f / __builtin_sqrtf(deg);
  };
  float di = disof(i);
  float acc = 0.0f;
#pragma unroll 4
  for (int k = 0; k < KK; ++k) {
    int s = nbr[i*KK + k];
    float ewk = (mx - de[i*KK + k]) / rng;
    float coef = (disof(s) * ewk) * di;            // (dis[s]*w)*dis[t]
    acc = fmaf(coef, xw[s*HH + lane], acc);
  }
  acc = fmaf(di * di, xw[i*HH + lane], acc);       // self loop last
  float hv = fmaxf(acc + b[lane], 0.0f);           // h1[i][lane]
  float acc2 = 0.0f;
#pragma unroll 16
  for (int k = 0; k < HH; ++k) {
    float hk = __shfl(hv, k, 64);
    acc2 = fmaf(hk, w2[k*HH + lane], acc2);
  }
  xw2[i*HH + lane] = acc2;
}

// ---------------------------------------------------------------- agg2 + relu + fc, inline ew/dis
__global__ __launch_bounds__(256) void agg_fc_kernel(const float* __restrict__ xw,
                                                     const int* __restrict__ nbr,
                                                     const float* __restrict__ de,
                                                     const float* __restrict__ sumd,
                                                     const unsigned* __restrict__ gmm,
                                                     const float* __restrict__ b,
                                                     const float* __restrict__ wfc,
                                                     const float* __restrict__ bfc,
                                                     const int* __restrict__ sid,
                                                     float* __restrict__ out) {
#pragma clang fp contract(off)
  int wv = threadIdx.x >> 6, lane = threadIdx.x & 63;
  int i = sid[(blockIdx.x << 2) + wv];
  float mx  = __uint_as_float(gmm[1]);
  float rng = mx - __uint_as_float(gmm[0]);
  float s16 = 16.0f * mx;
  auto disof = [&](int n) {
    float deg = 1.0f + (s16 - sumd[n]) / rng;
    return 1.0f / __builtin_sqrtf(deg);
  };
  float di = disof(i);
  float acc = 0.0f;
#pragma unroll 4
  for (int k = 0; k < KK; ++k) {
    int s = nbr[i*KK + k];
    float ewk = (mx - de[i*KK + k]) / rng;
    float coef = (disof(s) * ewk) * di;
    acc = fmaf(coef, xw[s*HH + lane], acc);
  }
  acc = fmaf(di * di, xw[i*HH + lane], acc);
  float v = fmaxf(acc + b[lane], 0.0f);            // h2 feature
  float p = v * wfc[lane];                         // h2 @ Wfc (F_OUT = 1)
#pragma unroll
  for (int off = 32; off > 0; off >>= 1) p = p + __shfl_xor(p, off, 64);
  if (lane == 0) out[i] = p + bfc[0];
}

// ---------------------------------------------------------------- launch
extern "C" void kernel_launch(void* const* d_in, const int* in_sizes, int n_in,
                              void* d_out, int out_size, void* d_ws, size_t ws_size,
                              hipStream_t stream) {
  (void)in_sizes; (void)n_in; (void)out_size; (void)ws_size;
  const float* x   = (const float*)d_in[0];
  const float* c   = (const float*)d_in[1];
  const float* W1  = (const float*)d_in[2];
  const float* b1  = (const float*)d_in[3];
  const float* W2  = (const float*)d_in[4];
  const float* b2  = (const float*)d_in[5];
  const float* Wfc = (const float*)d_in[6];
  const float* bfc = (const float*)d_in[7];
  float* out = (float*)d_out;

  char* ws = (char*)d_ws;
  size_t off = 0;
  auto alloc = [&](size_t bytes) -> void* {
    void* p = ws + off;
    off += (bytes + 255) & ~size_t(255);
    return p;
  };
  float4*   pack   = (float4*)  alloc(NN * sizeof(float4));         // 256 KB
  float4*   sorted = (float4*)  alloc(NN * sizeof(float4));         // 256 KB
  unsigned* cnt    = (unsigned*)alloc((NCELL+1) * sizeof(unsigned));// cnt + flag (zeroed together)
  unsigned* flag   = cnt + NCELL;
  unsigned* cstart = (unsigned*)alloc((NCELL+1) * sizeof(unsigned));
  unsigned* cursor = (unsigned*)alloc(NCELL * sizeof(unsigned));
  unsigned* cellid = (unsigned*)alloc(NN * sizeof(unsigned));       // 64 KB
  int*      sid    = (int*)     alloc(NN * sizeof(int));            // 64 KB
  int*      nbr    = (int*)     alloc(NE * sizeof(int));            // 1 MB
  float*    de     = (float*)   alloc(NE * sizeof(float));          // 1 MB (raw d)
  float*    sumd   = (float*)   alloc(NN * sizeof(float));          // 64 KB
  unsigned* gmm    = (unsigned*)alloc(2 * sizeof(unsigned));
  float*    xw1    = (float*)   alloc(NN * HH * sizeof(float));     // 4 MB
  float*    xw2    = (float*)   alloc(NN * HH * sizeof(float));     // 4 MB

  hipMemsetAsync(cnt, 0, (NCELL+1) * sizeof(unsigned), stream);
  prep_count_gemm1_kernel<<<NPC + G1B, 256, 0, stream>>>(c, x, W1, pack, cellid,
                                                         cnt, gmm, xw1);
  scan_scatter_kernel    <<<64,   256, 0, stream>>>(cnt, cstart, cursor, pack,
                                                    cellid, sorted, sid, flag);
  knn_kernel             <<<250,  256, 0, stream>>>(sorted, cstart, c, nbr, de,
                                                    sumd, gmm);
  agg_gemm2_kernel       <<<NN/4, 256, 0, stream>>>(xw1, nbr, de, sumd, gmm, b1,
                                                    sid, W2, xw2);
  agg_fc_kernel          <<<NN/4, 256, 0, stream>>>(xw2, nbr, de, sumd, gmm, b2,
                                                    Wfc, bfc, sid, out);
}